// Round 5
// baseline (100.634 us; speedup 1.0000x reference)
//
#include <hip/hip_runtime.h>

#define BETA2 25.0f
#define EPS 1e-9f
#define BLOCK 256
#define UN 8
#define CHUNK (BLOCK * UN)   // 2048 float4s per array per block

// d_ws layout (SoA, uint): [nblocks] tp | [nblocks] fp | [nblocks] fn

__device__ __forceinline__ void acc3(float t, float l, int& tp, int& fp, int& fn) {
    int tn = (t != 0.0f), ln = (l != 0.0f);
    tp += tn & ln;
    fp += tn & (ln ^ 1);
    fn += (tn ^ 1) & ln;
}

__global__ void __launch_bounds__(BLOCK) fbeta_count(const float4* __restrict__ t4,
                                                     const float4* __restrict__ l4,
                                                     unsigned int* __restrict__ partials,
                                                     int n4, int nblocks) {
    int tp = 0, fp = 0, fn = 0;
    const int base = blockIdx.x * CHUNK + threadIdx.x;

    if (blockIdx.x * CHUNK + CHUNK <= n4) {
        // Issue all 16 independent dwordx4 loads before consuming (max MLP).
        float4 tv[UN], lv[UN];
        #pragma unroll
        for (int k = 0; k < UN; ++k) {
            tv[k] = t4[base + k * BLOCK];
            lv[k] = l4[base + k * BLOCK];
        }
        #pragma unroll
        for (int k = 0; k < UN; ++k) {
            acc3(tv[k].x, lv[k].x, tp, fp, fn);
            acc3(tv[k].y, lv[k].y, tp, fp, fn);
            acc3(tv[k].z, lv[k].z, tp, fp, fn);
            acc3(tv[k].w, lv[k].w, tp, fp, fn);
        }
    } else {
        for (int i = base; i < n4; i += BLOCK) {
            float4 tv = t4[i];
            float4 lv = l4[i];
            acc3(tv.x, lv.x, tp, fp, fn);
            acc3(tv.y, lv.y, tp, fp, fn);
            acc3(tv.z, lv.z, tp, fp, fn);
            acc3(tv.w, lv.w, tp, fp, fn);
        }
    }

    // wave-64 reduction
    #pragma unroll
    for (int off = 32; off > 0; off >>= 1) {
        tp += __shfl_down(tp, off, 64);
        fp += __shfl_down(fp, off, 64);
        fn += __shfl_down(fn, off, 64);
    }

    // cross-wave reduction in LDS, plain per-block stores (no atomics)
    __shared__ int s[3][BLOCK / 64];
    const int wave = threadIdx.x >> 6;
    if ((threadIdx.x & 63) == 0) {
        s[0][wave] = tp;
        s[1][wave] = fp;
        s[2][wave] = fn;
    }
    __syncthreads();
    if (threadIdx.x == 0) {
        int btp = 0, bfp = 0, bfn = 0;
        #pragma unroll
        for (int w = 0; w < BLOCK / 64; ++w) {
            btp += s[0][w];
            bfp += s[1][w];
            bfn += s[2][w];
        }
        partials[blockIdx.x]               = (unsigned int)btp;
        partials[nblocks + blockIdx.x]     = (unsigned int)bfp;
        partials[2 * nblocks + blockIdx.x] = (unsigned int)bfn;
    }
}

__global__ void __launch_bounds__(BLOCK) fbeta_reduce(const unsigned int* __restrict__ partials,
                                                      float* __restrict__ out, int nblocks) {
    unsigned int tp = 0, fp = 0, fn = 0;
    for (int b = threadIdx.x; b < nblocks; b += BLOCK) {
        tp += partials[b];
        fp += partials[nblocks + b];
        fn += partials[2 * nblocks + b];
    }
    #pragma unroll
    for (int off = 32; off > 0; off >>= 1) {
        tp += __shfl_down(tp, off, 64);
        fp += __shfl_down(fp, off, 64);
        fn += __shfl_down(fn, off, 64);
    }
    __shared__ unsigned int s[3][BLOCK / 64];
    const int wave = threadIdx.x >> 6;
    if ((threadIdx.x & 63) == 0) {
        s[0][wave] = tp;
        s[1][wave] = fp;
        s[2][wave] = fn;
    }
    __syncthreads();
    if (threadIdx.x == 0) {
        float ftp = 0.f, ffp = 0.f, ffn = 0.f;
        #pragma unroll
        for (int w = 0; w < BLOCK / 64; ++w) {
            ftp += (float)s[0][w];
            ffp += (float)s[1][w];
            ffn += (float)s[2][w];
        }
        ftp += EPS; ffp += EPS; ffn += EPS;
        float precision = ftp / (ftp + ffp);
        float recall    = ftp / (ftp + ffn);
        out[0] = (1.0f + BETA2) * (precision * recall) / (BETA2 * precision + recall);
    }
}

extern "C" void kernel_launch(void* const* d_in, const int* in_sizes, int n_in,
                              void* d_out, int out_size, void* d_ws, size_t ws_size,
                              hipStream_t stream) {
    const float* targets = (const float*)d_in[0];
    const float* labels  = (const float*)d_in[1];
    float* out = (float*)d_out;
    unsigned int* partials = (unsigned int*)d_ws;

    const int n = in_sizes[0];          // 67108864
    const int n4 = n >> 2;              // 16777216 float4s
    const int nblocks = (n4 + CHUNK - 1) / CHUNK;   // 8192

    fbeta_count<<<nblocks, BLOCK, 0, stream>>>((const float4*)targets,
                                               (const float4*)labels,
                                               partials, n4, nblocks);
    fbeta_reduce<<<1, BLOCK, 0, stream>>>(partials, out, nblocks);
}